// Round 1
// 638.873 us; speedup vs baseline: 1.1410x; 1.1410x over previous
//
#include <hip/hip_runtime.h>
#include <hip/hip_bf16.h>
#include <type_traits>

#define BATCH  16
#define SEQ    1024
#define HIDDEN 1024
#define NHEAD  4
#define DHEAD  256
#define QKVN   2304   // (2*NHEAD+1)*DHEAD

typedef _Float16 f16x8 __attribute__((ext_vector_type(8)));
typedef float    f32x4 __attribute__((ext_vector_type(4)));

__device__ __forceinline__ void gll16(const void* g, void* l) {
  __builtin_amdgcn_global_load_lds(
      (const __attribute__((address_space(1))) unsigned int*)g,
      (__attribute__((address_space(3))) unsigned int*)l, 16, 0, 0);
}

// ---------------------------------------------------------------------------
// fp32 -> f16 elementwise (x pre-conversion)
// ---------------------------------------------------------------------------
__global__ __launch_bounds__(256) void f32_to_f16(
    const float* __restrict__ in, _Float16* __restrict__ out) {
  int i4 = blockIdx.x * 256 + threadIdx.x;
  float4 v = ((const float4*)in)[i4];
  _Float16 h4[4] = {(_Float16)v.x, (_Float16)v.y, (_Float16)v.z, (_Float16)v.w};
  *(uint2*)&out[(size_t)i4 * 4] = *(uint2*)h4;
}

// ---------------------------------------------------------------------------
// Transpose fp32 [R][C] -> f16 [C][R]
// ---------------------------------------------------------------------------
__global__ __launch_bounds__(256) void transpose_to_f16(
    const float* __restrict__ in, _Float16* __restrict__ out, int R, int C) {
  __shared__ float tile[64][65];
  int bc = blockIdx.x * 64, br = blockIdx.y * 64;
  int t = threadIdx.x;
  int tr = t >> 6, tc = t & 63;
  for (int i = 0; i < 64; i += 4)
    tile[tr + i][tc] = in[(size_t)(br + tr + i) * C + bc + tc];
  __syncthreads();
  for (int i = 0; i < 64; i += 4)
    out[(size_t)(bc + tr + i) * R + br + tc] = (_Float16)tile[tc][tr + i];
}

// ---------------------------------------------------------------------------
// Transpose v slice of qkv (f16) into vT[b][d][s]
// ---------------------------------------------------------------------------
__global__ __launch_bounds__(256) void transpose_v(
    const _Float16* __restrict__ qkv, _Float16* __restrict__ vT) {
  __shared__ _Float16 tile[64][65];
  int b = blockIdx.z;
  int s0 = blockIdx.x * 64, d0 = blockIdx.y * 64;
  int t = threadIdx.x;
  int tr = t >> 6, tc = t & 63;
  for (int i = 0; i < 64; i += 4)
    tile[tr + i][tc] = qkv[((size_t)(b * SEQ + s0 + tr + i)) * QKVN + 2 * NHEAD * DHEAD + d0 + tc];
  __syncthreads();
  for (int i = 0; i < 64; i += 4)
    vT[((size_t)(b * DHEAD + d0 + tr + i)) * SEQ + s0 + tc] = tile[tc][tr + i];
}

// ---------------------------------------------------------------------------
// GEMM (B^T): C[m][n] = sum_k A[m][k]*B[n][k]; A,B f16; 128x128 tile BK=32.
// ---------------------------------------------------------------------------
template <typename OT>
__global__ __launch_bounds__(256) void gemm_bt(
    const _Float16* __restrict__ A, const _Float16* __restrict__ B,
    OT* __restrict__ C, int M, int N, int K) {
  __shared__ __align__(16) _Float16 As[128][32];
  __shared__ __align__(16) _Float16 Bs[128][32];
  int bm = blockIdx.x * 128, bn = blockIdx.y * 128;
  int t = threadIdx.x;
  int w = t >> 6, L = t & 63, lane15 = L & 15, quad = L >> 4;
  int wr = (w >> 1) * 64, wc = (w & 1) * 64;
  f32x4 acc[4][4] = {};
  for (int k0 = 0; k0 < K; k0 += 32) {
    __syncthreads();
    for (int r = 0; r < 2; r++) {
      int u = t + r * 256;
      int row = u >> 2, c8 = u & 3;
      gll16(&A[(size_t)(bm + row) * K + k0 + c8 * 8], &As[row][c8 * 8]);
      gll16(&B[(size_t)(bn + row) * K + k0 + c8 * 8], &Bs[row][c8 * 8]);
    }
    __syncthreads();
    f16x8 af[4], bf[4];
    for (int i = 0; i < 4; i++) af[i] = *(f16x8*)&As[wr + i * 16 + lane15][quad * 8];
    for (int j = 0; j < 4; j++) bf[j] = *(f16x8*)&Bs[wc + j * 16 + lane15][quad * 8];
    for (int i = 0; i < 4; i++)
      for (int j = 0; j < 4; j++)
        acc[i][j] = __builtin_amdgcn_mfma_f32_16x16x32_f16(af[i], bf[j], acc[i][j], 0, 0, 0);
  }
  for (int i = 0; i < 4; i++)
    for (int j = 0; j < 4; j++) {
      int gr = bm + wr + i * 16 + quad * 4;
      int gc = bn + wc + j * 16 + lane15;
      for (int r = 0; r < 4; r++) {
        float v = acc[i][j][r];
        if constexpr (std::is_same_v<OT, float>)
          C[(size_t)(gr + r) * N + gc] = v;
        else
          C[(size_t)(gr + r) * N + gc] = (_Float16)v;
      }
    }
}

// ---------------------------------------------------------------------------
// Scores + softmax. DEFERRED softmax: phase A runs all QK^T MFMAs with a
// double-buffered K pipeline (stage-next -> compute-current -> barrier);
// phase B does ONE max/exp/sum pass over the register-resident strip
// (32 shfl total instead of 32 per si-tile; one exp per element instead of
// two). XCD-chunked block swizzle keeps each batch's K slice in one L2.
// Grid (SEQ/64, NHEAD, BATCH), 512 thr = 4 row-grp x 2 col-half.
// ---------------------------------------------------------------------------
__global__ __launch_bounds__(512, 2) void scores_norm_kernel(
    const _Float16* __restrict__ qkv, float* __restrict__ P) {
  // bijective XCD swizzle: 1024 blocks -> 8 chunks of 128 (2 batches/XCD)
  int lin = blockIdx.x + 16 * (blockIdx.y + 4 * blockIdx.z);
  int swz = (lin & 7) * 128 + (lin >> 3);
  int ti = swz & 15, n = (swz >> 4) & 3, b = swz >> 6;
  __shared__ __align__(16) _Float16 Qs[8][64][32];
  __shared__ __align__(16) _Float16 Ks[2][8][64][32];
  int t = threadIdx.x;
  int w = t >> 6, L = t & 63, lane15 = L & 15, quad = L >> 4;
  int r16 = (w & 3) * 16;   // row group
  int ch  = (w >> 2) * 32;  // col half
  // prologue: stage Q tile + K tile (si=0)
  for (int r = 0; r < 4; r++) {
    int u = t + r * 512;
    int kc = u >> 8, row = (u & 255) >> 2, c8 = u & 3;
    gll16(&qkv[((size_t)(b * SEQ + ti * 64 + row)) * QKVN + n * DHEAD + kc * 32 + c8 * 8],
          &Qs[kc][row][c8 * 8]);
    gll16(&qkv[((size_t)(b * SEQ + row)) * QKVN + NHEAD * DHEAD + n * DHEAD + kc * 32 + c8 * 8],
          &Ks[0][kc][row][c8 * 8]);
  }
  __syncthreads();
  // hoist Q fragments (LDS -> 32 VGPR, read once instead of per si-tile)
  f16x8 aq[8];
#pragma unroll
  for (int kc = 0; kc < 8; kc++) aq[kc] = *(f16x8*)&Qs[kc][r16 + lane15][quad * 8];
  f32x4 s[16][2];
  int trow = ti * 64 + r16 + quad * 4;
  const float scale = 0.0625f;
  // ---- phase A: MFMA everything, double-buffered K staging ----
#pragma unroll
  for (int si = 0; si < 16; si++) {
    if (si <= ti) {
      if (si < ti) {
        for (int r = 0; r < 4; r++) {
          int u = t + r * 512;
          int kc = u >> 8, row = (u & 255) >> 2, c8 = u & 3;
          gll16(&qkv[((size_t)(b * SEQ + (si + 1) * 64 + row)) * QKVN + NHEAD * DHEAD + n * DHEAD + kc * 32 + c8 * 8],
                &Ks[(si + 1) & 1][kc][row][c8 * 8]);
        }
      }
      s[si][0] = (f32x4){0.f, 0.f, 0.f, 0.f};
      s[si][1] = (f32x4){0.f, 0.f, 0.f, 0.f};
      for (int kc = 0; kc < 8; kc++) {
        for (int j = 0; j < 2; j++) {
          f16x8 bk = *(f16x8*)&Ks[si & 1][kc][ch + j * 16 + lane15][quad * 8];
          s[si][j] = __builtin_amdgcn_mfma_f32_16x16x32_f16(aq[kc], bk, s[si][j], 0, 0, 0);
        }
      }
      __syncthreads();  // drains vmcnt(0): next K landed; readers done with cur
    }
  }
  // ---- phase B: deferred softmax, one pass ----
  float m[4], l[4];
#pragma unroll
  for (int r = 0; r < 4; r++) {
    float mx = -INFINITY;
#pragma unroll
    for (int si = 0; si < 16; si++) {
      if (si <= ti) {
        for (int j = 0; j < 2; j++) {
          int col = si * 64 + ch + j * 16 + lane15;
          float v = s[si][j][r] * scale;
          if (col > trow + r) v = -1e9f;
          s[si][j][r] = v;
          mx = fmaxf(mx, v);
        }
      }
    }
    for (int off = 1; off < 16; off <<= 1) mx = fmaxf(mx, __shfl_xor(mx, off, 64));
    float sum = 0.f;
#pragma unroll
    for (int si = 0; si < 16; si++) {
      if (si <= ti) {
        for (int j = 0; j < 2; j++) {
          float p = __expf(s[si][j][r] - mx);
          s[si][j][r] = p;   // store exp(v - m_half); scaled by fac at write
          sum += p;
        }
      }
    }
    for (int off = 1; off < 16; off <<= 1) sum += __shfl_xor(sum, off, 64);
    m[r] = mx; l[r] = sum;
  }
  // merge the two col-halves' stats per row via LDS scratch (reuse Qs)
  __syncthreads();
  float* sM  = (float*)&Qs[0][0][0];  // [2][64]
  float* sL  = sM + 128;
  float* sMc = sM + 256;              // [64] merged max
  float* sRl = sM + 320;              // [64] merged 1/l
  if (lane15 == 0) {
    for (int r = 0; r < 4; r++) {
      sM[(w >> 2) * 64 + r16 + quad * 4 + r] = m[r];
      sL[(w >> 2) * 64 + r16 + quad * 4 + r] = l[r];
    }
  }
  __syncthreads();
  if (t < 64) {
    float m0 = sM[t], m1 = sM[64 + t], l0 = sL[t], l1 = sL[64 + t];
    float mc = fmaxf(m0, m1);
    float lc = l0 * __expf(m0 - mc) + l1 * __expf(m1 - mc);
    sMc[t] = mc;
    sRl[t] = 1.0f / lc;
  }
  __syncthreads();
  // per-row factor folding half-max -> global-max rescale and 1/l
  float fac[4];
  for (int r = 0; r < 4; r++) {
    int row = r16 + quad * 4 + r;
    fac[r] = __expf(m[r] - sMc[row]) * sRl[row];
  }
  size_t Pbase = ((size_t)(b * NHEAD + n)) * SEQ * SEQ;
  // write normalized P from registers (masked entries underflow to 0)
#pragma unroll
  for (int si = 0; si < 16; si++) {
    if (si <= ti) {
      for (int j = 0; j < 2; j++) {
        int col = si * 64 + ch + j * 16 + lane15;
        for (int r = 0; r < 4; r++)
          P[Pbase + (size_t)(trow + r) * SEQ + col] = s[si][j][r] * fac[r];
      }
    }
  }
  // zero-fill the strip's fully-masked columns (col4 >= (ti+1)*16)
  {
    float4 z = make_float4(0.f, 0.f, 0.f, 0.f);
    int c4min = (ti + 1) * 16;
    for (int u = t; u < 16384; u += 512) {
      int row = u >> 8, c4 = u & 255;
      if (c4 >= c4min)
        *(float4*)&P[Pbase + (size_t)(ti * 64 + row) * SEQ + c4 * 4] = z;
    }
  }
}

// ---------------------------------------------------------------------------
// Pmean[b][t][s] = f16( mean_n P[b][n][t][s] ), causal tiles only.
// Grid (si, ti, b) with si>ti blocks exiting immediately.
// ---------------------------------------------------------------------------
__global__ __launch_bounds__(256) void pmean_kernel(
    const float* __restrict__ P, _Float16* __restrict__ Pmean) {
  int si = blockIdx.x, ti = blockIdx.y, b = blockIdx.z;
  if (si > ti) return;
  int t = threadIdx.x;
  int row = t >> 2, c16 = (t & 3) * 16;
  size_t tile_off = (size_t)(ti * 64 + row) * SEQ + si * 64 + c16;
  float acc[16];
  for (int i = 0; i < 16; i++) acc[i] = 0.f;
  for (int n = 0; n < 4; n++) {
    const float* p = &P[((size_t)(b * NHEAD + n)) * SEQ * SEQ + tile_off];
    for (int q = 0; q < 4; q++) {
      float4 v = *(const float4*)(p + q * 4);
      acc[q * 4 + 0] += v.x; acc[q * 4 + 1] += v.y;
      acc[q * 4 + 2] += v.z; acc[q * 4 + 3] += v.w;
    }
  }
  _Float16 h[16];
  for (int i = 0; i < 16; i++) h[i] = (_Float16)(acc[i] * 0.25f);
  _Float16* pm = &Pmean[((size_t)(b * SEQ + ti * 64 + row)) * SEQ + si * 64 + c16];
  *(uint4*)pm = *(uint4*)h;
  *(uint4*)(pm + 8) = *(uint4*)(h + 8);
}

// ---------------------------------------------------------------------------
// m_attn[b][t][d] = sum_s Pmean[b][t][s] * v[b][s][d]  (f16 out)
// Re-gridded: (ti, d-quarter, b) = 1024 light blocks of 256 thr so ~4 blocks
// co-reside per CU (smooths causal load imbalance, 4x occupancy); si loop is
// double-buffered. XCD-chunked swizzle keeps per-batch vT/Pmean in one L2.
// ---------------------------------------------------------------------------
__global__ __launch_bounds__(256) void pv_kernel(
    const _Float16* __restrict__ Pmean, const _Float16* __restrict__ vT,
    _Float16* __restrict__ mattn) {
  int lin = blockIdx.x + 16 * (blockIdx.y + 4 * blockIdx.z);
  int swz = (lin & 7) * 128 + (lin >> 3);
  int ti = swz & 15, dq = (swz >> 4) & 3, b = swz >> 6;
  __shared__ __align__(16) _Float16 Pm[2][2][64][32];
  __shared__ __align__(16) _Float16 Vs[2][2][64][32];
  int t = threadIdx.x;
  int w = t >> 6, L = t & 63, lane15 = L & 15, quad = L >> 4;
  f32x4 acc[4] = {};
  // prologue: stage si=0
  for (int r = 0; r < 2; r++) {
    int u = t + r * 256;
    int kc = u >> 8, row = (u & 255) >> 2, c8 = u & 3;
    gll16(&Pmean[((size_t)(b * SEQ + ti * 64 + row)) * SEQ + kc * 32 + c8 * 8],
          &Pm[0][kc][row][c8 * 8]);
    gll16(&vT[((size_t)(b * DHEAD + dq * 64 + row)) * SEQ + kc * 32 + c8 * 8],
          &Vs[0][kc][row][c8 * 8]);
  }
  __syncthreads();
  for (int si = 0; si <= ti; si++) {
    int cb = si & 1;
    if (si < ti) {
      for (int r = 0; r < 2; r++) {
        int u = t + r * 256;
        int kc = u >> 8, row = (u & 255) >> 2, c8 = u & 3;
        gll16(&Pmean[((size_t)(b * SEQ + ti * 64 + row)) * SEQ + (si + 1) * 64 + kc * 32 + c8 * 8],
              &Pm[cb ^ 1][kc][row][c8 * 8]);
        gll16(&vT[((size_t)(b * DHEAD + dq * 64 + row)) * SEQ + (si + 1) * 64 + kc * 32 + c8 * 8],
              &Vs[cb ^ 1][kc][row][c8 * 8]);
      }
    }
#pragma unroll
    for (int kc = 0; kc < 2; kc++) {
      f16x8 ap = *(f16x8*)&Pm[cb][kc][w * 16 + lane15][quad * 8];
#pragma unroll
      for (int j = 0; j < 4; j++) {
        f16x8 bv = *(f16x8*)&Vs[cb][kc][j * 16 + lane15][quad * 8];
        acc[j] = __builtin_amdgcn_mfma_f32_16x16x32_f16(ap, bv, acc[j], 0, 0, 0);
      }
    }
    __syncthreads();
  }
  for (int j = 0; j < 4; j++) {
    int row = b * SEQ + ti * 64 + w * 16 + quad * 4;
    int col = dq * 64 + j * 16 + lane15;
    for (int r = 0; r < 4; r++)
      mattn[(size_t)(row + r) * DHEAD + col] = (_Float16)acc[j][r];
  }
}

// ---------------------------------------------------------------------------
// ws layout (f16 elems): wqkvT[2304*1024] | woutT[1024*256] | qkvb[16384*2304]
// | vT[16*256*1024].  After scores, qkvb is dead -> mattn = qkvb,
// Pmean = qkvb + 16384*256.  xh (x as f16) lives in P region until scores.
// ---------------------------------------------------------------------------
extern "C" void kernel_launch(void* const* d_in, const int* in_sizes, int n_in,
                              void* d_out, int out_size, void* d_ws, size_t ws_size,
                              hipStream_t stream) {
  const float* x     = (const float*)d_in[0];
  const float* w_qkv = (const float*)d_in[1];
  const float* w_out = (const float*)d_in[2];
  float* out = (float*)d_out;
  float* P   = out + (size_t)BATCH * SEQ * HIDDEN;

  _Float16* wqkvT = (_Float16*)d_ws;
  _Float16* woutT = wqkvT + (size_t)QKVN * HIDDEN;
  _Float16* qkvb  = woutT + (size_t)HIDDEN * DHEAD;
  _Float16* vT    = qkvb + (size_t)BATCH * SEQ * QKVN;
  _Float16* mattn = qkvb;                              // alias (qkvb dead after scores)
  _Float16* Pmean = qkvb + (size_t)BATCH * SEQ * DHEAD;
  _Float16* xh    = (_Float16*)P;                      // alias (overwritten by scores)

  f32_to_f16<<<BATCH * SEQ * HIDDEN / 1024, 256, 0, stream>>>(x, xh);
  transpose_to_f16<<<dim3(QKVN / 64, HIDDEN / 64), 256, 0, stream>>>(w_qkv, wqkvT, HIDDEN, QKVN);
  transpose_to_f16<<<dim3(HIDDEN / 64, DHEAD / 64), 256, 0, stream>>>(w_out, woutT, DHEAD, HIDDEN);
  gemm_bt<_Float16><<<dim3(BATCH * SEQ / 128, QKVN / 128), 256, 0, stream>>>(
      xh, wqkvT, qkvb, BATCH * SEQ, QKVN, HIDDEN);
  transpose_v<<<dim3(SEQ / 64, DHEAD / 64, BATCH), 256, 0, stream>>>(qkvb, vT);
  scores_norm_kernel<<<dim3(SEQ / 64, NHEAD, BATCH), 512, 0, stream>>>(qkvb, P);
  pmean_kernel<<<dim3(SEQ / 64, SEQ / 64, BATCH), 256, 0, stream>>>(P, Pmean);
  pv_kernel<<<dim3(SEQ / 64, 4, BATCH), 256, 0, stream>>>(Pmean, vT, mattn);
  gemm_bt<float><<<dim3(BATCH * SEQ / 128, HIDDEN / 128), 256, 0, stream>>>(
      mattn, woutT, out, BATCH * SEQ, HIDDEN, DHEAD);
}